// Round 13
// baseline (23.267 us; speedup 1.0000x reference)
//
#include <hip/hip_runtime.h>
#include <hip/hip_bf16.h>

#define N_POINTS 16384
#define N_GAUSS  3200
#define N_CLASSES 14
#define NCHUNK (N_GAUSS / 32)   // 100 chunks of 32 gaussians

typedef _Float16 half8  __attribute__((ext_vector_type(8)));   // 4 VGPRs
typedef _Float16 half2v __attribute__((ext_vector_type(2)));
typedef float    f32x4  __attribute__((ext_vector_type(4)));

// d_ws layout (294,400 B <= proven-safe 307,200):
//   [0, 204800)        crec: [3200][32] f16 -- K-slots [Ch(10)|Cl(10)|Ch(10)|0,0]
//   [204800, 294400)   semP: [14][3200] f16 -- chunk-permuted semantics
#define WS_CREC_OFF 0
#define WS_SEMP_OFF 204800

// ---------------------------------------------------------------------------
// Prep. C[10] quadratic-form coefficients (P-form):
//   arg = Sum_k P[k]*C[k],  P = [x^2,y^2,z^2,xy,xz,yz,x,y,z,1]
//   exp2(arg) = opacity * exp(-0.5*q)
// K=32 record packs all three precision terms of one contraction:
//   A = [Ch|Cl|Ch|00] x B = [Ph|Ph|Pl|00] -> Ch.Ph + Cl.Ph + Ch.Pl
// Semantics f16, permuted to PV K-order: p = grpW*8 + gt*4 + i <->
// g = c*32 + gt*16 + grpW*4 + i.
// ---------------------------------------------------------------------------
__global__ void gauss_prep_kernel(const float* __restrict__ means,
                                  const float* __restrict__ scales,
                                  const float* __restrict__ rotations,
                                  const float* __restrict__ opacities,
                                  const float* __restrict__ semantics,
                                  _Float16* __restrict__ crec,
                                  _Float16* __restrict__ semP) {
    const int g = blockIdx.x * blockDim.x + threadIdx.x;
    if (g >= N_GAUSS) return;

    float qw = rotations[g * 4 + 0];
    float qx = rotations[g * 4 + 1];
    float qy = rotations[g * 4 + 2];
    float qz = rotations[g * 4 + 3];
    float inv = 1.0f / sqrtf(qw * qw + qx * qx + qy * qy + qz * qz);
    qw *= inv; qx *= inv; qy *= inv; qz *= inv;

    float r00 = 1.0f - 2.0f * (qy * qy + qz * qz);
    float r01 = 2.0f * (qx * qy - qw * qz);
    float r02 = 2.0f * (qx * qz + qw * qy);
    float r10 = 2.0f * (qx * qy + qw * qz);
    float r11 = 1.0f - 2.0f * (qx * qx + qz * qz);
    float r12 = 2.0f * (qy * qz - qw * qx);
    float r20 = 2.0f * (qx * qz - qw * qy);
    float r21 = 2.0f * (qy * qz + qw * qx);
    float r22 = 1.0f - 2.0f * (qx * qx + qy * qy);

    float sx = scales[g * 3 + 0];
    float sy = scales[g * 3 + 1];
    float sz = scales[g * 3 + 2];
    float iv0 = 1.0f / (sx * sx);
    float iv1 = 1.0f / (sy * sy);
    float iv2 = 1.0f / (sz * sz);

    float a00 = iv0 * r00 * r00 + iv1 * r10 * r10 + iv2 * r20 * r20;
    float a01 = iv0 * r00 * r01 + iv1 * r10 * r11 + iv2 * r20 * r21;
    float a02 = iv0 * r00 * r02 + iv1 * r10 * r12 + iv2 * r20 * r22;
    float a11 = iv0 * r01 * r01 + iv1 * r11 * r11 + iv2 * r21 * r21;
    float a12 = iv0 * r01 * r02 + iv1 * r11 * r12 + iv2 * r21 * r22;
    float a22 = iv0 * r02 * r02 + iv1 * r12 * r12 + iv2 * r22 * r22;

    float mx = means[g * 3 + 0];
    float my = means[g * 3 + 1];
    float mz = means[g * 3 + 2];
    float amx = a00 * mx + a01 * my + a02 * mz;
    float amy = a01 * mx + a11 * my + a12 * mz;
    float amz = a02 * mx + a12 * my + a22 * mz;
    float muAmu = mx * amx + my * amy + mz * amz;

    const float k = -0.72134752044448170368f;   // -0.5 * log2(e)

    float C[10];
    C[0] = k * a00;  C[1] = k * a11;  C[2] = k * a22;
    C[3] = 2.0f * k * a01;  C[4] = 2.0f * k * a02;  C[5] = 2.0f * k * a12;
    C[6] = -2.0f * k * amx; C[7] = -2.0f * k * amy; C[8] = -2.0f * k * amz;
    C[9] = k * muAmu + log2f(opacities[g]);

    _Float16* rec = crec + (size_t)g * 32;
#pragma unroll
    for (int kk = 0; kk < 10; ++kk) {
        _Float16 h = (_Float16)C[kk];
        rec[kk]      = h;                              // Ch at K 0..9
        rec[10 + kk] = (_Float16)(C[kk] - (float)h);   // Cl at K 10..19
        rec[20 + kk] = h;                              // Ch again at K 20..29
    }
    rec[30] = (_Float16)0; rec[31] = (_Float16)0;

    const int cidx = g >> 5, r = g & 31;
    const int gt = r >> 4, grpW = (r >> 2) & 3, i = r & 3;
    const int p = grpW * 8 + gt * 4 + i;
#pragma unroll
    for (int c = 0; c < N_CLASSES; ++c)
        semP[(size_t)c * N_GAUSS + cidx * 32 + p] = (_Float16)semantics[g * N_CLASSES + c];
}

// ---------------------------------------------------------------------------
// Main: 512 blocks (2/CU -> 4 waves/SIMD) x 512 threads (8 waves). Each
// block owns a 32-POINT group and ALL 100 chunks; wave wid owns 12-13.
// R12 ran 64-pt blocks at 1/CU = 2 waves/SIMD: the per-chunk serial chain
// (Q-MFMA -> exp2 -> pack -> LDS write -> read -> PV-MFMA) left the SIMD
// ~70% idle. Halving the tile doubles co-resident waves; work/wave halves;
// still no atomics, no zeroing, plain coalesced stores.
// Per chunk (32 pts x 32 g): 4 Q-MFMAs ([Ch|Cl|Ch]x[Ph|Ph|Pl] one-shot
// 3-term), 16 exp2/lane, cvt_pk, 2 swizzled b128 LDS writes, 2 A-frag
// reads + 2 PV MFMAs vs semP. Next-chunk A/bS prefetch rotation kept.
// Epilogue: LDS 8-way reduce + plain coalesced stores (448 floats/block).
// ---------------------------------------------------------------------------
__launch_bounds__(512, 4)
__global__ void gauss_occ_main_kernel(const float* __restrict__ xyz,
                                      const _Float16* __restrict__ crec,
                                      const _Float16* __restrict__ semP,
                                      float* __restrict__ out) {
    __shared__ unsigned int wbuf[8][32][16];   // 16 KiB: per-wave 2 KiB tile

    const int tid  = threadIdx.x;
    const int lane = tid & 63;
    const int wid  = __builtin_amdgcn_readfirstlane(tid >> 6);
    const int pg   = blockIdx.x;                     // 0..511 point-group (32 pts)
    const int c0 = (wid * NCHUNK) >> 3;              // wid*12.5
    const int c1 = ((wid + 1) * NCHUNK) >> 3;

    const int m   = lane & 15;
    const int mm  = (m < N_CLASSES) ? m : (N_CLASSES - 1);
    const int grp = lane >> 4;
    const int frs = (m >> 1) & 3;          // swizzle key for rows s*16+m
    const int wsz = (lane >> 1) & 3;       // swizzle key for row lane (row=lane<32)

    const int pt = pg * 32 + (lane & 31);
    const float x = xyz[pt * 3 + 0];
    const float y = xyz[pt * 3 + 1];
    const float z = xyz[pt * 3 + 2];

    unsigned int (*wrow)[16] = wbuf[wid];

    // ---- one-time: stage expanded 32-slot B-row [Ph|Ph|Pl|00] per point ----
    if (lane < 32) {
        float P[10] = {x * x, y * y, z * z, x * y, x * z, y * z, x, y, z, 1.0f};
        _Float16 Ph[10], Pl[10];
#pragma unroll
        for (int j = 0; j < 10; ++j) {
            Ph[j] = (_Float16)P[j];
            Pl[j] = (_Float16)(P[j] - (float)Ph[j]);   // exact residual
        }
        half8 b0, b1, b2, b3;
#pragma unroll
        for (int j = 0; j < 8; ++j) b0[j] = Ph[j];                 // K0-7
        b1[0] = Ph[8]; b1[1] = Ph[9];
#pragma unroll
        for (int j = 0; j < 6; ++j) b1[2 + j] = Ph[j];             // K8-15
#pragma unroll
        for (int j = 0; j < 4; ++j) { b2[j] = Ph[6 + j]; b2[4 + j] = Pl[j]; }  // K16-23
#pragma unroll
        for (int j = 0; j < 6; ++j) b3[j] = Pl[4 + j];             // K24-29
        b3[6] = (_Float16)0; b3[7] = (_Float16)0;                  // K30-31
        *(half8*)&wrow[lane][(0 ^ wsz) * 4] = b0;
        *(half8*)&wrow[lane][(1 ^ wsz) * 4] = b1;
        *(half8*)&wrow[lane][(2 ^ wsz) * 4] = b2;
        *(half8*)&wrow[lane][(3 ^ wsz) * 4] = b3;
    }

    // gather Q B-fragments: lane (m,grp) needs block grp of point s*16+m
    half8 f1[2];
#pragma unroll
    for (int s = 0; s < 2; ++s)
        f1[s] = *(const half8*)&wrow[s * 16 + m][(grp ^ frs) * 4];

    f32x4 acc0 = {0.f, 0.f, 0.f, 0.f};
    f32x4 acc1 = {0.f, 0.f, 0.f, 0.f};
    const f32x4 z4 = {0.f, 0.f, 0.f, 0.f};

    // ---- software-pipelined main loop: prefetch chunk c+1 during c ----
    size_t rb = ((size_t)(c0 * 32 + m)) * 32 + (size_t)grp * 8;
    half8 A0 = *(const half8*)(crec + rb);
    half8 A1 = *(const half8*)(crec + rb + 16 * 32);
    half8 bS = *(const half8*)(semP + (size_t)mm * N_GAUSS + c0 * 32 + grp * 8);

    for (int c = c0; c < c1; ++c) {
        const int cn = (c + 1 < c1) ? (c + 1) : c;   // uniform; last iter re-loads
        const size_t rbn = ((size_t)(cn * 32 + m)) * 32 + (size_t)grp * 8;
        const half8 nA0 = *(const half8*)(crec + rbn);
        const half8 nA1 = *(const half8*)(crec + rbn + 16 * 32);
        const half8 nbS = *(const half8*)(semP + (size_t)mm * N_GAUSS + cn * 32 + grp * 8);

        // ---- Q-MFMAs + exp + pack + staged write, per point-subtile s ----
#pragma unroll
        for (int s = 0; s < 2; ++s) {
            f32x4 t0 = __builtin_amdgcn_mfma_f32_16x16x32_f16(A0, f1[s], z4, 0, 0, 0);
            f32x4 t1 = __builtin_amdgcn_mfma_f32_16x16x32_f16(A1, f1[s], z4, 0, 0, 0);

            half2v h01, h23, h45, h67;
            h01[0] = (_Float16)__builtin_amdgcn_exp2f(t0[0]);
            h01[1] = (_Float16)__builtin_amdgcn_exp2f(t0[1]);
            h23[0] = (_Float16)__builtin_amdgcn_exp2f(t0[2]);
            h23[1] = (_Float16)__builtin_amdgcn_exp2f(t0[3]);
            h45[0] = (_Float16)__builtin_amdgcn_exp2f(t1[0]);
            h45[1] = (_Float16)__builtin_amdgcn_exp2f(t1[1]);
            h67[0] = (_Float16)__builtin_amdgcn_exp2f(t1[2]);
            h67[1] = (_Float16)__builtin_amdgcn_exp2f(t1[3]);

            *(uint4*)&wrow[s * 16 + m][(grp ^ frs) * 4] =
                make_uint4(__builtin_bit_cast(unsigned int, h01),
                           __builtin_bit_cast(unsigned int, h23),
                           __builtin_bit_cast(unsigned int, h45),
                           __builtin_bit_cast(unsigned int, h67));
        }

        // ---- PV-phase: A-frag reads + 2 MFMAs ----
        const half8 a0 = *(const half8*)&wrow[ 0 + m][(grp ^ frs) * 4];
        const half8 a1 = *(const half8*)&wrow[16 + m][(grp ^ frs) * 4];
        acc0 = __builtin_amdgcn_mfma_f32_16x16x32_f16(a0, bS, acc0, 0, 0, 0);
        acc1 = __builtin_amdgcn_mfma_f32_16x16x32_f16(a1, bS, acc1, 0, 0, 0);

        A0 = nA0; A1 = nA1; bS = nbS;
    }

    // ---- epilogue: dump acc into own LDS region, 8-way reduce, store ----
    float* red = (float*)&wbuf[0][0][0];   // [8][32][16] f32 view
#pragma unroll
    for (int i = 0; i < 4; ++i) {
        red[wid * 512 + ( 0 + grp * 4 + i) * 16 + m] = acc0[i];
        red[wid * 512 + (16 + grp * 4 + i) * 16 + m] = acc1[i];
    }
    __syncthreads();

    // 448 outputs per block; idx = l*14+cc -> address pg*448+idx: coalesced
    if (tid < 32 * N_CLASSES) {
        const int l = tid / N_CLASSES;
        const int cc = tid - l * N_CLASSES;
        float s = 0.0f;
#pragma unroll
        for (int wq = 0; wq < 8; ++wq) s += red[wq * 512 + l * 16 + cc];
        out[(size_t)pg * (32 * N_CLASSES) + tid] = s;
    }
}

extern "C" void kernel_launch(void* const* d_in, const int* in_sizes, int n_in,
                              void* d_out, int out_size, void* d_ws, size_t ws_size,
                              hipStream_t stream) {
    const float* xyz       = (const float*)d_in[0];
    const float* means     = (const float*)d_in[1];
    const float* scales    = (const float*)d_in[2];
    const float* rotations = (const float*)d_in[3];
    const float* opacities = (const float*)d_in[4];
    const float* semantics = (const float*)d_in[5];
    float* out = (float*)d_out;

    _Float16* crec = (_Float16*)((char*)d_ws + WS_CREC_OFF);
    _Float16* semP = (_Float16*)((char*)d_ws + WS_SEMP_OFF);

    hipLaunchKernelGGL(gauss_prep_kernel,
                       dim3(13), dim3(256), 0, stream,
                       means, scales, rotations, opacities, semantics, crec, semP);

    hipLaunchKernelGGL(gauss_occ_main_kernel,
                       dim3(512), dim3(512), 0, stream,
                       xyz, crec, semP, out);
}